// Round 1
// baseline (14770.891 us; speedup 1.0000x reference)
//
#include <hip/hip_runtime.h>
#include <hip/hip_fp16.h>

#define T_LEN 4096
#define HID   256
#define G4    1024

typedef unsigned int u32;
typedef _Float16 half2_t __attribute__((ext_vector_type(2)));

__device__ __forceinline__ float dot2f(u32 w, u32 h, float acc) {
#if __has_builtin(__builtin_amdgcn_fdot2)
    return __builtin_amdgcn_fdot2(__builtin_bit_cast(half2_t, w),
                                  __builtin_bit_cast(half2_t, h), acc, false);
#else
    __half2 wh = __builtin_bit_cast(__half2, w);
    __half2 hh = __builtin_bit_cast(__half2, h);
    float2 wf = __half22float2(wh), hf = __half22float2(hh);
    return acc + wf.x * hf.x + wf.y * hf.y;
#endif
}

__device__ __forceinline__ u32 pack2(float a, float b) {
    unsigned short lo = __half_as_ushort(__float2half(a));
    unsigned short hi = __half_as_ushort(__float2half(b));
    return ((u32)hi << 16) | (u32)lo;
}

// ---------------- transpose: out[k*N+n] = in[n*K+k] ----------------
__global__ void k_transpose(const float* __restrict__ in, float* __restrict__ out,
                            int N, int K) {
    int q = blockIdx.x * 256 + threadIdx.x;
    if (q >= N * K) return;
    int n = q / K, k = q % K;
    out[(size_t)k * N + n] = in[q];
}

// ---------------- pack Whh (1024x256 fp32) -> reg-pack + lds-pack (f16x2) ----
// rp: [512 threads][192 u32]  thread tid rows r0=tid (k<192), r1=tid+512 (k<192)
// lp: [1024 rows][32 u32]     k in [192,256)
__global__ void k_pack_whh(const float* __restrict__ W,
                           u32* __restrict__ rp, u32* __restrict__ lp) {
    int q = blockIdx.x * 256 + threadIdx.x;
    if (q < 512 * 192) {
        int tid = q / 192, j = q % 192;
        int row = (j < 96) ? tid : tid + 512;
        int p = j % 96;
        rp[q] = pack2(W[row * 256 + 2 * p], W[row * 256 + 2 * p + 1]);
    } else {
        int qq = q - 512 * 192;
        if (qq < 1024 * 32) {
            int row = qq / 32, j = qq % 32;
            lp[qq] = pack2(W[row * 256 + 192 + 2 * j], W[row * 256 + 192 + 2 * j + 1]);
        }
    }
}

// ---------------- generic GEMM: C[M,N] = A[M,K] @ Wt[K,N] (+bias / relu / cosine)
// grid (M/16, N/256), block 256. mode: 0 bias, 1 bias+relu, 2 cosine epilogue
__global__ __launch_bounds__(256) void k_gemm(
    const float* __restrict__ A, const float* __restrict__ Wt,
    const float* __restrict__ bias, const float* __restrict__ norms,
    float* __restrict__ C, int M, int N, int K, int mode) {
    __shared__ float As[16 * 512];
    const int tid = threadIdx.x;
    const int m0 = blockIdx.x * 16;
    const int n  = blockIdx.y * 256 + tid;

    for (int i = tid; i < 16 * K; i += 256) As[i] = A[(size_t)m0 * K + i];
    __syncthreads();

    float acc[16];
#pragma unroll
    for (int m = 0; m < 16; ++m) acc[m] = 0.f;

#pragma unroll 4
    for (int k = 0; k < K; ++k) {
        float w = Wt[(size_t)k * N + n];
#pragma unroll
        for (int m = 0; m < 16; ++m) acc[m] += As[m * K + k] * w;
    }

    float bn = bias ? bias[n] : 0.f;
#pragma unroll
    for (int m = 0; m < 16; ++m) {
        float v = acc[m] + bn;
        if (mode == 1) v = fmaxf(v, 0.f);
        if (mode == 2) {
            float d = norms[m0 + m] * norms[n];
            v = 1.f - fmaxf(acc[m] / d, 1e-6f);
        }
        C[(size_t)(m0 + m) * N + n] = v;
    }
}

// ---------------- row norms of e (4096 x 256) ----------------
__global__ void k_norms(const float* __restrict__ e, float* __restrict__ norms) {
    int i = blockIdx.x, lane = threadIdx.x;
    float s = 0.f;
    for (int k = lane; k < 256; k += 64) { float v = e[i * 256 + k]; s += v * v; }
    for (int off = 32; off; off >>= 1) s += __shfl_down(s, off);
    if (lane == 0) norms[i] = sqrtf(s);
}

// ---------------- the recurrent scan: one block per direction ----------------
// xs: [2][T][1024] precomputed x@Wih.T + b (dir-major)
// rp: [2][512*192], lp: [2][1024*32]
// hout: [T][512], direction d writes columns d*256 .. d*256+255
__global__ __launch_bounds__(512, 2) void k_scan(
    const float* __restrict__ xs, const u32* __restrict__ rp,
    const u32* __restrict__ lp, float* __restrict__ hout) {
    __shared__ alignas(16) u32 wl[1024 * 34];   // 136 KB, pad 34 vs 32
    __shared__ alignas(16) u32 hlds[128];       // 256 f16 packed
    __shared__ float zsh[512];                  // f,o gate exchange

    const int tid = threadIdx.x;
    const int dir = blockIdx.x;
    xs += (size_t)dir * (T_LEN * G4);
    rp += (size_t)dir * (512 * 192);
    lp += (size_t)dir * (1024 * 32);

    for (int i = tid; i < 1024 * 32; i += 512) {
        int row = i >> 5, j = i & 31;
        wl[row * 34 + j] = lp[i];
    }
    if (tid < 128) hlds[tid] = 0u;

    u32 regw[192];
    {
        const uint4* rp4 = (const uint4*)(rp + (size_t)tid * 192);
#pragma unroll
        for (int p = 0; p < 48; ++p) {
            uint4 v = rp4[p];
            regw[4 * p + 0] = v.x; regw[4 * p + 1] = v.y;
            regw[4 * p + 2] = v.z; regw[4 * p + 3] = v.w;
        }
    }
    const int r0 = tid, r1 = tid + 512;
    float cst = 0.f;
    __syncthreads();

    int tt = dir ? (T_LEN - 1) : 0;
    float xn0 = xs[(size_t)tt * G4 + r0];
    float xn1 = xs[(size_t)tt * G4 + r1];

    for (int t = 0; t < T_LEN; ++t) {
        float a0 = xn0, a1 = xn1;
        int tn = dir ? ((t + 1 < T_LEN) ? T_LEN - 2 - t : 0)
                     : ((t + 1 < T_LEN) ? t + 1 : T_LEN - 1);
        xn0 = xs[(size_t)tn * G4 + r0];   // prefetch next step
        xn1 = xs[(size_t)tn * G4 + r1];

        // k in [0,192): register weights
#pragma unroll
        for (int c = 0; c < 3; ++c) {
            u32 hh[32];
#pragma unroll
            for (int q = 0; q < 8; ++q) {
                uint4 v = *(const uint4*)&hlds[c * 32 + 4 * q];
                hh[4 * q + 0] = v.x; hh[4 * q + 1] = v.y;
                hh[4 * q + 2] = v.z; hh[4 * q + 3] = v.w;
            }
#pragma unroll
            for (int p = 0; p < 32; ++p) {
                a0 = dot2f(regw[c * 32 + p],      hh[p], a0);
                a1 = dot2f(regw[96 + c * 32 + p], hh[p], a1);
            }
        }
        // k in [192,256): LDS weights
#pragma unroll
        for (int s = 0; s < 4; ++s) {
            u32 hh[8], w0[8], w1[8];
            uint4 hv0 = *(const uint4*)&hlds[96 + 8 * s];
            uint4 hv1 = *(const uint4*)&hlds[96 + 8 * s + 4];
            hh[0] = hv0.x; hh[1] = hv0.y; hh[2] = hv0.z; hh[3] = hv0.w;
            hh[4] = hv1.x; hh[5] = hv1.y; hh[6] = hv1.z; hh[7] = hv1.w;
#pragma unroll
            for (int u = 0; u < 4; ++u) {
                uint2 wa = *(const uint2*)&wl[r0 * 34 + 8 * s + 2 * u];
                w0[2 * u] = wa.x; w0[2 * u + 1] = wa.y;
                uint2 wb = *(const uint2*)&wl[r1 * 34 + 8 * s + 2 * u];
                w1[2 * u] = wb.x; w1[2 * u + 1] = wb.y;
            }
#pragma unroll
            for (int p = 0; p < 8; ++p) {
                a0 = dot2f(w0[p], hh[p], a0);
                a1 = dot2f(w1[p], hh[p], a1);
            }
        }

        // rows: tid<256 -> a0=i[n],a1=g[n]; tid>=256 -> a0=f[n],a1=o[n]
        if (tid >= 256) { zsh[tid - 256] = a0; zsh[256 + (tid - 256)] = a1; }
        __syncthreads();
        if (tid < 256) {
            float zi = a0, zg = a1;
            float zf = zsh[tid], zo = zsh[256 + tid];
            float si = 1.f / (1.f + __expf(-zi));
            float sf = 1.f / (1.f + __expf(-zf));
            float so = 1.f / (1.f + __expf(-zo));
            float tg = 1.f - 2.f / (__expf(2.f * zg) + 1.f);
            cst = sf * cst + si * tg;
            float th = 1.f - 2.f / (__expf(2.f * cst) + 1.f);
            float hv = so * th;
            hout[(size_t)tt * 512 + dir * 256 + tid] = hv;
            ((__half*)hlds)[tid] = __float2half(hv);
        }
        __syncthreads();
        tt = tn;
    }
}

// ---------------- launcher ----------------
extern "C" void kernel_launch(void* const* d_in, const int* in_sizes, int n_in,
                              void* d_out, int out_size, void* d_ws, size_t ws_size,
                              hipStream_t stream) {
    const float* x       = (const float*)d_in[0];
    const float* wih_l0f = (const float*)d_in[1];
    const float* whh_l0f = (const float*)d_in[2];
    const float* b_l0f   = (const float*)d_in[3];
    const float* wih_l0b = (const float*)d_in[4];
    const float* whh_l0b = (const float*)d_in[5];
    const float* b_l0b   = (const float*)d_in[6];
    const float* wih_l1f = (const float*)d_in[7];
    const float* whh_l1f = (const float*)d_in[8];
    const float* b_l1f   = (const float*)d_in[9];
    const float* wih_l1b = (const float*)d_in[10];
    const float* whh_l1b = (const float*)d_in[11];
    const float* b_l1b   = (const float*)d_in[12];
    const float* fc1_w   = (const float*)d_in[13];
    const float* fc1_b   = (const float*)d_in[14];
    const float* fc2_w   = (const float*)d_in[15];
    const float* fc2_b   = (const float*)d_in[16];
    float* outp = (float*)d_out;

    char* ws = (char*)d_ws;
    size_t off = 0;
    auto alloc = [&](size_t nbytes) {
        char* p = ws + off;
        off += (nbytes + 255) & ~(size_t)255;
        return p;
    };
    float* xs0   = (float*)alloc((size_t)2 * T_LEN * G4 * 4);
    float* xs1   = (float*)alloc((size_t)2 * T_LEN * G4 * 4);
    float* h1    = (float*)alloc((size_t)T_LEN * 512 * 4);
    float* h2    = (float*)alloc((size_t)T_LEN * 512 * 4);
    float* zb    = (float*)alloc((size_t)T_LEN * 256 * 4);
    float* eb    = (float*)alloc((size_t)T_LEN * 256 * 4);
    float* etb   = (float*)alloc((size_t)T_LEN * 256 * 4);
    float* nrm   = (float*)alloc((size_t)T_LEN * 4);
    float* wt0f  = (float*)alloc((size_t)128 * 1024 * 4);
    float* wt0b  = (float*)alloc((size_t)128 * 1024 * 4);
    float* wt1f  = (float*)alloc((size_t)512 * 1024 * 4);
    float* wt1b  = (float*)alloc((size_t)512 * 1024 * 4);
    float* wtf1  = (float*)alloc((size_t)512 * 256 * 4);
    float* wtf2  = (float*)alloc((size_t)256 * 256 * 4);
    u32*   rp0   = (u32*)alloc((size_t)2 * 512 * 192 * 4);
    u32*   lp0   = (u32*)alloc((size_t)2 * 1024 * 32 * 4);
    u32*   rp1   = (u32*)alloc((size_t)2 * 512 * 192 * 4);
    u32*   lp1   = (u32*)alloc((size_t)2 * 1024 * 32 * 4);

    // weight transposes
    k_transpose<<<(1024 * 128 + 255) / 256, 256, 0, stream>>>(wih_l0f, wt0f, 1024, 128);
    k_transpose<<<(1024 * 128 + 255) / 256, 256, 0, stream>>>(wih_l0b, wt0b, 1024, 128);
    k_transpose<<<(1024 * 512 + 255) / 256, 256, 0, stream>>>(wih_l1f, wt1f, 1024, 512);
    k_transpose<<<(1024 * 512 + 255) / 256, 256, 0, stream>>>(wih_l1b, wt1b, 1024, 512);
    k_transpose<<<(256 * 512 + 255) / 256, 256, 0, stream>>>(fc1_w, wtf1, 256, 512);
    k_transpose<<<(256 * 256 + 255) / 256, 256, 0, stream>>>(fc2_w, wtf2, 256, 256);

    // recurrent weight packs
    const int packN = (512 * 192 + 1024 * 32 + 255) / 256;
    k_pack_whh<<<packN, 256, 0, stream>>>(whh_l0f, rp0,                lp0);
    k_pack_whh<<<packN, 256, 0, stream>>>(whh_l0b, rp0 + 512 * 192,    lp0 + 1024 * 32);
    k_pack_whh<<<packN, 256, 0, stream>>>(whh_l1f, rp1,                lp1);
    k_pack_whh<<<packN, 256, 0, stream>>>(whh_l1b, rp1 + 512 * 192,    lp1 + 1024 * 32);

    dim3 g1024(T_LEN / 16, 4);
    // layer 0 input projections
    k_gemm<<<g1024, 256, 0, stream>>>(x, wt0f, b_l0f, nullptr, xs0, T_LEN, 1024, 128, 0);
    k_gemm<<<g1024, 256, 0, stream>>>(x, wt0b, b_l0b, nullptr, xs0 + (size_t)T_LEN * G4, T_LEN, 1024, 128, 0);
    // layer 0 scan (both directions)
    k_scan<<<2, 512, 0, stream>>>(xs0, rp0, lp0, h1);
    // layer 1 input projections
    k_gemm<<<g1024, 256, 0, stream>>>(h1, wt1f, b_l1f, nullptr, xs1, T_LEN, 1024, 512, 0);
    k_gemm<<<g1024, 256, 0, stream>>>(h1, wt1b, b_l1b, nullptr, xs1 + (size_t)T_LEN * G4, T_LEN, 1024, 512, 0);
    // layer 1 scan
    k_scan<<<2, 512, 0, stream>>>(xs1, rp1, lp1, h2);
    // FC head
    k_gemm<<<dim3(T_LEN / 16, 1), 256, 0, stream>>>(h2, wtf1, fc1_b, nullptr, zb, T_LEN, 256, 512, 1);
    k_gemm<<<dim3(T_LEN / 16, 1), 256, 0, stream>>>(zb, wtf2, fc2_b, nullptr, eb, T_LEN, 256, 256, 0);
    // cosine-similarity output
    k_transpose<<<(T_LEN * 256 + 255) / 256, 256, 0, stream>>>(eb, etb, T_LEN, 256);
    k_norms<<<T_LEN, 64, 0, stream>>>(eb, nrm);
    k_gemm<<<dim3(T_LEN / 16, T_LEN / 256), 256, 0, stream>>>(eb, etb, nullptr, nrm, outp, T_LEN, T_LEN, 256, 2);
}